// Round 16
// baseline (120.883 us; speedup 1.0000x reference)
//
#include <hip/hip_runtime.h>

#define CC 192
#define NN 16384
#define XST 198   // kproj Xs stride (elems) = 99 dw (odd) — R9-proven staging layout
#define SST2 134  // kproj Ss bounce stride (67 dw, odd -> conflict-free)
#define QXST 104  // kq Xs stride (elems)
#define QST 200   // kq SsT stride (elems)

typedef unsigned short u16;
typedef __attribute__((ext_vector_type(4))) float f32x4;
typedef __attribute__((ext_vector_type(8))) __bf16 bf16x8;
typedef __attribute__((ext_vector_type(8))) u16 u16x8;
typedef __attribute__((ext_vector_type(4))) u16 u16x4;

union FragU { u16x8 u; bf16x8 b; };

__device__ __forceinline__ u16 f2bf(float f) {
  union { float f; unsigned u; } x; x.f = f;
  return (u16)((x.u + 0x7FFFu + ((x.u >> 16) & 1u)) >> 16);  // RNE
}
__device__ __forceinline__ float bf2f(u16 h) {
  union { unsigned u; float f; } x; x.u = ((unsigned)h) << 16;
  return x.f;
}

// K/V projection — R15 body scaled to 512 thr / 128 tokens (TLP retry with
// linear writes): Xs/Ss overlaid in one 51.5KB buffer -> 3 blocks/CU (24 waves).
// Output tile-major [b][tile128][192][128] bf16, 48KB contiguous per block.
// z=0: Sexp = exp(Wk@k+bk); z=1: Vbuf = Wv@v+bv.
__global__ __launch_bounds__(512, 2)
void kproj(const float* __restrict__ k, const float* __restrict__ v,
           const u16* __restrict__ Wb, const float* __restrict__ bk,
           const float* __restrict__ bv, u16* __restrict__ Sexp,
           u16* __restrict__ Vbuf)
{
  __shared__ __align__(16) u16 buf[192 * SST2];  // 51.5 KB; Xs overlay then Ss
  u16 (*Xs)[XST] = reinterpret_cast<u16(*)[XST]>(buf);    // [128][198] = 50.7 KB
  u16 (*Ss)[SST2] = reinterpret_cast<u16(*)[SST2]>(buf);  // [192][134]

  const int b = blockIdx.y, pj = blockIdx.z;
  const int blk = blockIdx.x;                  // 0..127 (128 tokens each)
  const int t0 = blk * 128;
  const int tid = threadIdx.x;
  const int wv = tid >> 6, lane = tid & 63;
  const int lg = (lane >> 4) & 3, lc = lane & 15;
  const int wr = wv >> 1, wc = wv & 1;         // e-quadrant / token-half
  const int e0 = wr * 48;
  const int tg = tid & 31, chq = tid >> 5;     // token-group(4) / channel-slot(0..15)

  const float* xb = (pj ? v : k) + (size_t)b * CC * NN;
  const u16* Wp = Wb + (pj ? 2 : 1) * 36864;
  const float* bias = pj ? bv : bk;
  u16* outp = pj ? Vbuf : Sexp;

  // ---- issue all X loads: 12 x f32x4/thread, rows read as 512B chunks ----
  f32x4 p[12];
#pragma unroll
  for (int i = 0; i < 12; ++i)
    p[i] = *reinterpret_cast<const f32x4*>(xb + (size_t)(i * 16 + chq) * NN + t0 + tg * 4);

  // ---- issue all W-frag loads (L2/L3-hot) ----
  FragU wfr[6][3];
#pragma unroll
  for (int ks = 0; ks < 6; ++ks)
#pragma unroll
    for (int et = 0; et < 3; ++et)
      wfr[ks][et].u = *reinterpret_cast<const u16x8*>(
          &Wp[(e0 + et * 16 + lc) * 192 + ks * 32 + lg * 8]);

  // ---- cvt + transposed LDS writes ----
#pragma unroll
  for (int i = 0; i < 12; ++i) {
    const int ch = i * 16 + chq;
    Xs[tg * 4 + 0][ch] = f2bf(p[i][0]);
    Xs[tg * 4 + 1][ch] = f2bf(p[i][1]);
    Xs[tg * 4 + 2][ch] = f2bf(p[i][2]);
    Xs[tg * 4 + 3][ch] = f2bf(p[i][3]);
  }
  __syncthreads();

  // ---- 6 MFMA k-steps ----
  f32x4 acc[3][4];
#pragma unroll
  for (int et = 0; et < 3; ++et)
#pragma unroll
    for (int nt = 0; nt < 4; ++nt) acc[et][nt] = f32x4{0.f, 0.f, 0.f, 0.f};

#pragma unroll
  for (int ks = 0; ks < 6; ++ks) {
    FragU bb[4];
#pragma unroll
    for (int nt = 0; nt < 4; ++nt)
      bb[nt].u = *reinterpret_cast<const u16x8*>(
          &Xs[wc * 64 + nt * 16 + lc][ks * 32 + lg * 8]);
#pragma unroll
    for (int et = 0; et < 3; ++et)
#pragma unroll
      for (int nt = 0; nt < 4; ++nt)
        acc[et][nt] = __builtin_amdgcn_mfma_f32_16x16x32_bf16(wfr[ks][et].b, bb[nt].b,
                                                             acc[et][nt], 0, 0, 0);
  }
  __syncthreads();   // Xs reads complete before overwriting as Ss

  // ---- bias (+exp for K) -> Ss[e][tok128] bounce ----
#pragma unroll
  for (int et = 0; et < 3; ++et)
#pragma unroll
    for (int r = 0; r < 4; ++r) {
      const int e = e0 + et * 16 + lg * 4 + r;
      const float bbv = bias[e];
#pragma unroll
      for (int nt = 0; nt < 4; ++nt) {
        float val = acc[et][nt][r] + bbv;
        if (!pj) val = __expf(val);        // |kp| small; no max-sub needed
        Ss[e][wc * 64 + nt * 16 + lc] = f2bf(val);
      }
    }
  __syncthreads();

  // ---- linear tile write: 48KB contiguous, 1KB/wave-instr ----
  u16* dst = outp + (size_t)(b * 128 + blk) * 24576;
#pragma unroll
  for (int j = 0; j < 6; ++j) {
    const int f0 = tid * 8 + j * 4096;
    const int row = f0 >> 7, tok = f0 & 127;
    u16x8 vv = *reinterpret_cast<const u16x8*>(&Ss[row][tok]);
    *reinterpret_cast<u16x8*>(&dst[f0]) = vv;
  }
}

// ctx partials, 128-token tile-major inputs; phantom all-ones V-row computes
// ksum into the dv==24 slot for free. block = (256-token slab, batch); 8 waves.
__global__ __launch_bounds__(512, 2)
void kctx(const u16* __restrict__ Sexp, const u16* __restrict__ Vbuf,
          float* __restrict__ part)
{
  const int b = blockIdx.y, slab = blockIdx.x;   // 64 slabs x 256 tokens
  const int tid = threadIdx.x;
  const int h = tid >> 6;
  const int lg = (tid >> 4) & 3, lc = tid & 15;

  u16x8 ones;
#pragma unroll
  for (int j = 0; j < 8; ++j) ones[j] = 0x3F80;  // 1.0 bf16

  f32x4 cacc[2][2];
#pragma unroll
  for (int mt = 0; mt < 2; ++mt)
#pragma unroll
    for (int nt = 0; nt < 2; ++nt) cacc[mt][nt] = f32x4{0.f, 0.f, 0.f, 0.f};

#pragma unroll
  for (int ks = 0; ks < 8; ++ks) {
    const int tile = slab * 2 + (ks >> 2);       // 128-token tile index
    const int tokin = (ks & 3) * 32 + lg * 8;    // 0..127 within tile
    const size_t tbase = (size_t)(b * 128 + tile) * 24576;
    FragU av[2], bs[2];
#pragma unroll
    for (int mt = 0; mt < 2; ++mt) {
      int row = h * 24 + mt * 16 + lc;   // rows >= h*24+24 feed masked outputs
      if (row > 191) row = 191;
      av[mt].u = *reinterpret_cast<const u16x8*>(&Vbuf[tbase + row * 128 + tokin]);
      bs[mt].u = *reinterpret_cast<const u16x8*>(&Sexp[tbase + row * 128 + tokin]);
    }
    if (lc == 8) av[1].u = ones;         // phantom dv==24 row -> ksum
#pragma unroll
    for (int mt = 0; mt < 2; ++mt)
#pragma unroll
      for (int nt = 0; nt < 2; ++nt)
        cacc[mt][nt] = __builtin_amdgcn_mfma_f32_16x16x32_bf16(
            av[mt].b, bs[nt].b, cacc[mt][nt], 0, 0, 0);
  }

  // part[b][slab][h][dv*24+d], dv<25 (dv==24 = ksum partial); stride 600
  float* pp = part + (((size_t)(b * 64 + slab)) * 8 + h) * 600;
#pragma unroll
  for (int mt = 0; mt < 2; ++mt)
#pragma unroll
    for (int nt = 0; nt < 2; ++nt)
#pragma unroll
      for (int r = 0; r < 4; ++r) {
        const int dv = mt * 16 + lg * 4 + r;
        const int d = nt * 16 + lc;
        if (dv < 25 && d < 24) pp[dv * 24 + d] = cacc[mt][nt][r];
      }
}

// Reduce 64 slab partials + normalize by the phantom ksum row (dv==24)
__global__ void kr2(const float* __restrict__ part, float* __restrict__ ctx)
{
  const int idx = blockIdx.x * 256 + threadIdx.x;
  if (idx >= 4608) return;
  const int b = blockIdx.y;
  const int h = idx / 576, rem = idx % 576;
  const int dv = rem / 24, d = rem % 24;
  float s1 = 0.f, s2 = 0.f;
#pragma unroll 4
  for (int j = 0; j < 64; ++j) {
    const float* pp = part + (((size_t)(b * 64 + j)) * 8 + h) * 600;
    s1 += pp[dv * 24 + d];
    s2 += pp[576 + d];
  }
  ctx[(size_t)b * 4608 + h * 576 + dv * 24 + d] = s1 / s2;
}

// Meff[b][o][h*24+d] = sum_dv Wo[o][h*24+dv] * ctx[b][h][dv*24+d]
__global__ void km(const float* __restrict__ Wo, const float* __restrict__ ctx,
                   u16* __restrict__ Meff)
{
  const int o = blockIdx.x, b = blockIdx.y, j = threadIdx.x;
  const int h = j / 24, d = j % 24;
  const float* Wrow = Wo + o * 192 + h * 24;
  const float* crow = ctx + (size_t)b * 4608 + h * 576 + d;
  float acc = 0.f;
#pragma unroll
  for (int dv = 0; dv < 24; ++dv) acc += Wrow[dv] * crow[dv * 24];
  Meff[(b * 192 + o) * 192 + j] = f2bf(acc);
}

// One 192x192 (W) @ 192x64 (x fp32->bf16) GEMM (R7-exact — empirically best kq).
__device__ __forceinline__ void gemm_stage_compute(
    const float* __restrict__ xb, const u16* __restrict__ Wp,
    int t0, int tid, f32x4 acc[3][4], u16 (*Xs)[QXST])
{
  const int lg = (tid >> 4) & 3, lc = tid & 15;
  const int wave = tid >> 6, e0 = wave * 48;
  const int sn = tid & 63, scg = tid >> 6;
#pragma unroll
  for (int et = 0; et < 3; ++et)
#pragma unroll
    for (int nt = 0; nt < 4; ++nt)
      acc[et][nt] = f32x4{0.f, 0.f, 0.f, 0.f};

#pragma unroll
  for (int hf = 0; hf < 2; ++hf) {
#pragma unroll
    for (int i = 0; i < 6; ++i) {
      int cl = scg * 4 + i * 16;
      const float* src = xb + (size_t)(hf * 96 + cl) * NN + t0 + sn;
      u16x4 p;
      p[0] = f2bf(src[0]);
      p[1] = f2bf(src[NN]);
      p[2] = f2bf(src[2 * NN]);
      p[3] = f2bf(src[3 * NN]);
      *reinterpret_cast<u16x4*>(&Xs[sn][cl]) = p;
    }
    __syncthreads();
#pragma unroll
    for (int ks = 0; ks < 3; ++ks) {
      FragU a[3], bb[4];
#pragma unroll
      for (int et = 0; et < 3; ++et)
        a[et].u = *reinterpret_cast<const u16x8*>(
            &Wp[(e0 + et * 16 + lc) * 192 + hf * 96 + ks * 32 + lg * 8]);
#pragma unroll
      for (int nt = 0; nt < 4; ++nt)
        bb[nt].u = *reinterpret_cast<const u16x8*>(&Xs[nt * 16 + lc][ks * 32 + lg * 8]);
#pragma unroll
      for (int et = 0; et < 3; ++et)
#pragma unroll
        for (int nt = 0; nt < 4; ++nt)
          acc[et][nt] = __builtin_amdgcn_mfma_f32_16x16x32_bf16(a[et].b, bb[nt].b,
                                                               acc[et][nt], 0, 0, 0);
    }
    __syncthreads();
  }
}

// Q kernel (R7-exact, (256,2)): q-proj -> SsT -> softmax over d -> Meff GEMM -> out.
__global__ __launch_bounds__(256, 2)
void kq(const float* __restrict__ q, const u16* __restrict__ Wb,
        const float* __restrict__ bq, const u16* __restrict__ Meff,
        const float* __restrict__ bo, float* __restrict__ out)
{
  __shared__ __align__(16) u16 Xs[64][QXST];
  __shared__ __align__(16) u16 SsT[64][QST];

  const int b = blockIdx.y;
  const int t0 = blockIdx.x * 64;
  const int tid = threadIdx.x;
  const int lg = (tid >> 4) & 3, lc = tid & 15;
  const int wave = tid >> 6, e0 = wave * 48;
  const u16* Mb = Meff + b * 36864;

  f32x4 acc[3][4];

  gemm_stage_compute(q + (size_t)b * CC * NN, Wb, t0, tid, acc, Xs);
#pragma unroll
  for (int et = 0; et < 3; ++et)
#pragma unroll
    for (int r = 0; r < 4; ++r) {
      int e = e0 + et * 16 + lg * 4 + r;
      float bias = bq[e];
#pragma unroll
      for (int nt = 0; nt < 4; ++nt)
        SsT[nt * 16 + lc][e] = f2bf(acc[et][nt][r] + bias);
    }
  __syncthreads();

#pragma unroll
  for (int ii = 0; ii < 2; ++ii) {
    const int item = ii * 256 + tid;
    const int n = item & 63, h = item >> 6;
    u16* rowp = &SsT[n][h * 24];
    float vals[24];
    float m = -1e30f;
#pragma unroll
    for (int d = 0; d < 24; ++d) {
      vals[d] = bf2f(rowp[d]);
      m = fmaxf(m, vals[d]);
    }
    float s = 0.f;
#pragma unroll
    for (int d = 0; d < 24; ++d) { vals[d] = __expf(vals[d] - m); s += vals[d]; }
    const float inv = 1.f / s;
#pragma unroll
    for (int d = 0; d < 24; ++d) rowp[d] = f2bf(vals[d] * inv);
  }
  __syncthreads();

#pragma unroll
  for (int et = 0; et < 3; ++et)
#pragma unroll
    for (int nt = 0; nt < 4; ++nt) acc[et][nt] = f32x4{0.f, 0.f, 0.f, 0.f};
#pragma unroll
  for (int ks = 0; ks < 6; ++ks) {
    FragU a[3], bb[4];
#pragma unroll
    for (int et = 0; et < 3; ++et)
      a[et].u = *reinterpret_cast<const u16x8*>(
          &Mb[(e0 + et * 16 + lc) * 192 + ks * 32 + lg * 8]);
#pragma unroll
    for (int nt = 0; nt < 4; ++nt)
      bb[nt].u = *reinterpret_cast<const u16x8*>(&SsT[nt * 16 + lc][ks * 32 + lg * 8]);
#pragma unroll
    for (int et = 0; et < 3; ++et)
#pragma unroll
      for (int nt = 0; nt < 4; ++nt)
        acc[et][nt] = __builtin_amdgcn_mfma_f32_16x16x32_bf16(a[et].b, bb[nt].b,
                                                             acc[et][nt], 0, 0, 0);
  }

#pragma unroll
  for (int et = 0; et < 3; ++et)
#pragma unroll
    for (int r = 0; r < 4; ++r) {
      int row = e0 + et * 16 + lg * 4 + r;
      float bias = bo[row];
#pragma unroll
      for (int nt = 0; nt < 4; ++nt)
        out[(size_t)(b * 192 + row) * NN + t0 + nt * 16 + lc] = acc[et][nt][r] + bias;
    }
}

// Convert Wq/Wk/Wv to bf16 (packed [3][192][192]).
__global__ void kz(const float* __restrict__ Wq, const float* __restrict__ Wk,
                   const float* __restrict__ Wv, u16* __restrict__ Wb)
{
  const int i = blockIdx.x * 256 + threadIdx.x;
  if (i < 110592) {
    const float* src = (i < 36864) ? Wq : (i < 73728) ? Wk : Wv;
    Wb[i] = f2bf(src[i % 36864]);
  }
}

extern "C" void kernel_launch(void* const* d_in, const int* in_sizes, int n_in,
                              void* d_out, int out_size, void* d_ws, size_t ws_size,
                              hipStream_t stream)
{
  const float* q  = (const float*)d_in[0];
  const float* k  = (const float*)d_in[1];
  const float* v  = (const float*)d_in[2];
  const float* Wq = (const float*)d_in[3];
  const float* bq = (const float*)d_in[4];
  const float* Wk = (const float*)d_in[5];
  const float* bk = (const float*)d_in[6];
  const float* Wv = (const float*)d_in[7];
  const float* bv = (const float*)d_in[8];
  const float* Wo = (const float*)d_in[9];
  const float* bo = (const float*)d_in[10];
  float* out = (float*)d_out;

  // workspace carve (256B-aligned); total ~56 MB
  char* w = (char*)d_ws;
  u16*   Wb   = (u16*)(w);                     // 221184 B
  u16*   Sexp = (u16*)(w + 221184);            // 25165824 B : [4][128][192][128] bf16
  u16*   Vbuf = (u16*)(w + 25387008);          // 25165824 B : same tile-major layout
  float* part = (float*)(w + 50552832);        // 4915200 B : [4][64][8][600]
  float* ctx  = (float*)(w + 55468032);        // 73728 B : [4][8][576]
  u16*   Meff = (u16*)(w + 55541760);          // 294912 B : [4][192][192] bf16

  hipLaunchKernelGGL(kz, dim3(432), dim3(256), 0, stream, Wq, Wk, Wv, Wb);
  hipLaunchKernelGGL(kproj, dim3(128, 4, 2), dim3(512), 0, stream,
                     k, v, Wb, bk, bv, Sexp, Vbuf);
  hipLaunchKernelGGL(kctx, dim3(64, 4), dim3(512), 0, stream, Sexp, Vbuf, part);
  hipLaunchKernelGGL(kr2, dim3(18, 4), dim3(256), 0, stream, part, ctx);
  hipLaunchKernelGGL(km, dim3(192, 4), dim3(192), 0, stream, Wo, ctx, Meff);
  hipLaunchKernelGGL(kq, dim3(256, 4), dim3(256), 0, stream, q, Wb, bq, Meff, bo, out);
}

// Round 17
// 100.258 us; speedup vs baseline: 1.2057x; 1.2057x over previous
//
#include <hip/hip_runtime.h>

#define CC 192
#define NN 16384
#define XST 198   // kproj Xs stride (elems) = 99 dw (odd) — R9-proven staging layout
#define SST 72    // kproj Ss out-bounce stride (elems) = 36 dw; rows 144B (16B-aligned)
#define QXST 104  // kq Xs stride (elems)
#define QST 200   // kq SsT stride (elems)

typedef unsigned short u16;
typedef __attribute__((ext_vector_type(4))) float f32x4;
typedef __attribute__((ext_vector_type(8))) __bf16 bf16x8;
typedef __attribute__((ext_vector_type(8))) u16 u16x8;
typedef __attribute__((ext_vector_type(4))) u16 u16x4;

union FragU { u16x8 u; bf16x8 b; };

__device__ __forceinline__ u16 f2bf(float f) {
  union { float f; unsigned u; } x; x.f = f;
  return (u16)((x.u + 0x7FFFu + ((x.u >> 16) & 1u)) >> 16);  // RNE
}
__device__ __forceinline__ float bf2f(u16 h) {
  union { unsigned u; float f; } x; x.u = ((unsigned)h) << 16;
  return x.f;
}

// XCD-aware tile swizzle: blocks x ≡ c (mod 8) run on XCD c; map them to a
// contiguous 32-tile span so each XCD reads sequential 256B chunks (page hits).
__device__ __forceinline__ int xcd_tile(int x) { return (x & 7) * 32 + (x >> 3); }

// K/V projection — R15-exact body + XCD tile swizzle.
// z=0: Sexp = exp(Wk@k+bk); z=1: Vbuf = Wv@v+bv. Output tile-major
// [b][tile][192][64] bf16, 24.6KB contiguous burst per block.
__global__ __launch_bounds__(256, 2)
void kproj(const float* __restrict__ k, const float* __restrict__ v,
           const u16* __restrict__ Wb, const float* __restrict__ bk,
           const float* __restrict__ bv, u16* __restrict__ Sexp,
           u16* __restrict__ Vbuf)
{
  __shared__ __align__(16) u16 buf[192 * SST];   // 27.6 KB; Xs overlay then Ss
  u16 (*Xs)[XST] = reinterpret_cast<u16(*)[XST]>(buf);
  u16 (*Ss)[SST] = reinterpret_cast<u16(*)[SST]>(buf);

  const int b = blockIdx.y, pj = blockIdx.z;
  const int tile = xcd_tile(blockIdx.x);       // 0..255 (64 tokens each)
  const int t0 = tile * 64;
  const int tid = threadIdx.x;
  const int lg = (tid >> 4) & 3, lc = tid & 15;
  const int wave = tid >> 6, e0 = wave * 48;
  const int tg = tid & 15, chq = tid >> 4;     // token-group / channel-quad

  const float* xb = (pj ? v : k) + (size_t)b * CC * NN;
  const u16* Wp = Wb + (pj ? 2 : 1) * 36864;
  const float* bias = pj ? bv : bk;
  u16* outp = pj ? Vbuf : Sexp;

  // ---- issue all X loads (HBM, long pole) ----
  f32x4 p[12];
#pragma unroll
  for (int i = 0; i < 12; ++i)
    p[i] = *reinterpret_cast<const f32x4*>(xb + (size_t)(i * 16 + chq) * NN + t0 + tg * 4);

  // ---- issue all W-frag loads (L2/L3-hot) ----
  FragU wfr[6][3];
#pragma unroll
  for (int ks = 0; ks < 6; ++ks)
#pragma unroll
    for (int et = 0; et < 3; ++et)
      wfr[ks][et].u = *reinterpret_cast<const u16x8*>(
          &Wp[(e0 + et * 16 + lc) * 192 + ks * 32 + lg * 8]);

  // ---- cvt + transposed LDS writes ----
#pragma unroll
  for (int i = 0; i < 12; ++i) {
    const int ch = i * 16 + chq;
    Xs[tg * 4 + 0][ch] = f2bf(p[i][0]);
    Xs[tg * 4 + 1][ch] = f2bf(p[i][1]);
    Xs[tg * 4 + 2][ch] = f2bf(p[i][2]);
    Xs[tg * 4 + 3][ch] = f2bf(p[i][3]);
  }
  __syncthreads();

  // ---- 6 MFMA k-steps, zero in-loop global loads ----
  f32x4 acc[3][4];
#pragma unroll
  for (int et = 0; et < 3; ++et)
#pragma unroll
    for (int nt = 0; nt < 4; ++nt) acc[et][nt] = f32x4{0.f, 0.f, 0.f, 0.f};

#pragma unroll
  for (int ks = 0; ks < 6; ++ks) {
    FragU bb[4];
#pragma unroll
    for (int nt = 0; nt < 4; ++nt)
      bb[nt].u = *reinterpret_cast<const u16x8*>(&Xs[nt * 16 + lc][ks * 32 + lg * 8]);
#pragma unroll
    for (int et = 0; et < 3; ++et)
#pragma unroll
      for (int nt = 0; nt < 4; ++nt)
        acc[et][nt] = __builtin_amdgcn_mfma_f32_16x16x32_bf16(wfr[ks][et].b, bb[nt].b,
                                                             acc[et][nt], 0, 0, 0);
  }
  __syncthreads();   // MFMA ds_reads of Xs complete before overwriting as Ss

  // ---- bias (+exp for K) -> Ss[e][tok] bounce ----
#pragma unroll
  for (int et = 0; et < 3; ++et)
#pragma unroll
    for (int r = 0; r < 4; ++r) {
      const int e = e0 + et * 16 + lg * 4 + r;
      const float bbv = bias[e];
#pragma unroll
      for (int nt = 0; nt < 4; ++nt) {
        float val = acc[et][nt][r] + bbv;
        if (!pj) val = __expf(val);        // |kp| small; no max-sub needed
        Ss[e][nt * 16 + lc] = f2bf(val);
      }
    }
  __syncthreads();

  // ---- linear tile write: 24.6KB contiguous, coalesced 1KB/wave-instr ----
  u16* dst = outp + (size_t)(b * 256 + tile) * 12288;
#pragma unroll
  for (int j = 0; j < 6; ++j) {
    const int f0 = tid * 8 + j * 2048;
    const int row = f0 >> 6, tokin = f0 & 63;
    u16x8 vv = *reinterpret_cast<const u16x8*>(&Ss[row][tokin]);
    *reinterpret_cast<u16x8*>(&dst[f0]) = vv;
  }
}

// ctx partials, tile-major inputs; phantom all-ones V-row computes ksum into
// the dv==24 slot for free. block = (256-token slab, batch); 8 waves. No LDS.
__global__ __launch_bounds__(512, 2)
void kctx(const u16* __restrict__ Sexp, const u16* __restrict__ Vbuf,
          float* __restrict__ part)
{
  const int b = blockIdx.y, slab = blockIdx.x;   // 64 slabs x 256 tokens
  const int tid = threadIdx.x;
  const int h = tid >> 6;
  const int lg = (tid >> 4) & 3, lc = tid & 15;

  u16x8 ones;
#pragma unroll
  for (int j = 0; j < 8; ++j) ones[j] = 0x3F80;  // 1.0 bf16

  f32x4 cacc[2][2];
#pragma unroll
  for (int mt = 0; mt < 2; ++mt)
#pragma unroll
    for (int nt = 0; nt < 2; ++nt) cacc[mt][nt] = f32x4{0.f, 0.f, 0.f, 0.f};

#pragma unroll
  for (int ks = 0; ks < 8; ++ks) {
    const int tile = slab * 4 + (ks >> 1);
    const int tokin = (ks & 1) * 32 + lg * 8;
    const size_t tbase = (size_t)(b * 256 + tile) * 12288;
    FragU av[2], bs[2];
#pragma unroll
    for (int mt = 0; mt < 2; ++mt) {
      int row = h * 24 + mt * 16 + lc;   // rows >= h*24+24 feed masked outputs
      if (row > 191) row = 191;
      av[mt].u = *reinterpret_cast<const u16x8*>(&Vbuf[tbase + row * 64 + tokin]);
      bs[mt].u = *reinterpret_cast<const u16x8*>(&Sexp[tbase + row * 64 + tokin]);
    }
    if (lc == 8) av[1].u = ones;         // phantom dv==24 row -> ksum
#pragma unroll
    for (int mt = 0; mt < 2; ++mt)
#pragma unroll
      for (int nt = 0; nt < 2; ++nt)
        cacc[mt][nt] = __builtin_amdgcn_mfma_f32_16x16x32_bf16(
            av[mt].b, bs[nt].b, cacc[mt][nt], 0, 0, 0);
  }

  // part[b][slab][h][dv*24+d], dv<25 (dv==24 = ksum partial); stride 600
  float* pp = part + (((size_t)(b * 64 + slab)) * 8 + h) * 600;
#pragma unroll
  for (int mt = 0; mt < 2; ++mt)
#pragma unroll
    for (int nt = 0; nt < 2; ++nt)
#pragma unroll
      for (int r = 0; r < 4; ++r) {
        const int dv = mt * 16 + lg * 4 + r;
        const int d = nt * 16 + lc;
        if (dv < 25 && d < 24) pp[dv * 24 + d] = cacc[mt][nt][r];
      }
}

// Reduce 64 slab partials + normalize by the phantom ksum row (dv==24)
__global__ void kr2(const float* __restrict__ part, float* __restrict__ ctx)
{
  const int idx = blockIdx.x * 256 + threadIdx.x;
  if (idx >= 4608) return;
  const int b = blockIdx.y;
  const int h = idx / 576, rem = idx % 576;
  const int dv = rem / 24, d = rem % 24;
  float s1 = 0.f, s2 = 0.f;
#pragma unroll 4
  for (int j = 0; j < 64; ++j) {
    const float* pp = part + (((size_t)(b * 64 + j)) * 8 + h) * 600;
    s1 += pp[dv * 24 + d];
    s2 += pp[576 + d];
  }
  ctx[(size_t)b * 4608 + h * 576 + dv * 24 + d] = s1 / s2;
}

// Meff[b][o][h*24+d] = sum_dv Wo[o][h*24+dv] * ctx[b][h][dv*24+d]
__global__ void km(const float* __restrict__ Wo, const float* __restrict__ ctx,
                   u16* __restrict__ Meff)
{
  const int o = blockIdx.x, b = blockIdx.y, j = threadIdx.x;
  const int h = j / 24, d = j % 24;
  const float* Wrow = Wo + o * 192 + h * 24;
  const float* crow = ctx + (size_t)b * 4608 + h * 576 + d;
  float acc = 0.f;
#pragma unroll
  for (int dv = 0; dv < 24; ++dv) acc += Wrow[dv] * crow[dv * 24];
  Meff[(b * 192 + o) * 192 + j] = f2bf(acc);
}

// One 192x192 (W) @ 192x64 (x fp32->bf16) GEMM (R7-exact — empirically best kq).
__device__ __forceinline__ void gemm_stage_compute(
    const float* __restrict__ xb, const u16* __restrict__ Wp,
    int t0, int tid, f32x4 acc[3][4], u16 (*Xs)[QXST])
{
  const int lg = (tid >> 4) & 3, lc = tid & 15;
  const int wave = tid >> 6, e0 = wave * 48;
  const int sn = tid & 63, scg = tid >> 6;
#pragma unroll
  for (int et = 0; et < 3; ++et)
#pragma unroll
    for (int nt = 0; nt < 4; ++nt)
      acc[et][nt] = f32x4{0.f, 0.f, 0.f, 0.f};

#pragma unroll
  for (int hf = 0; hf < 2; ++hf) {
#pragma unroll
    for (int i = 0; i < 6; ++i) {
      int cl = scg * 4 + i * 16;
      const float* src = xb + (size_t)(hf * 96 + cl) * NN + t0 + sn;
      u16x4 p;
      p[0] = f2bf(src[0]);
      p[1] = f2bf(src[NN]);
      p[2] = f2bf(src[2 * NN]);
      p[3] = f2bf(src[3 * NN]);
      *reinterpret_cast<u16x4*>(&Xs[sn][cl]) = p;
    }
    __syncthreads();
#pragma unroll
    for (int ks = 0; ks < 3; ++ks) {
      FragU a[3], bb[4];
#pragma unroll
      for (int et = 0; et < 3; ++et)
        a[et].u = *reinterpret_cast<const u16x8*>(
            &Wp[(e0 + et * 16 + lc) * 192 + hf * 96 + ks * 32 + lg * 8]);
#pragma unroll
      for (int nt = 0; nt < 4; ++nt)
        bb[nt].u = *reinterpret_cast<const u16x8*>(&Xs[nt * 16 + lc][ks * 32 + lg * 8]);
#pragma unroll
      for (int et = 0; et < 3; ++et)
#pragma unroll
        for (int nt = 0; nt < 4; ++nt)
          acc[et][nt] = __builtin_amdgcn_mfma_f32_16x16x32_bf16(a[et].b, bb[nt].b,
                                                               acc[et][nt], 0, 0, 0);
    }
    __syncthreads();
  }
}

// Q kernel (R7-exact, (256,2)) + XCD tile swizzle: q-proj -> SsT -> softmax ->
// Meff GEMM -> out.
__global__ __launch_bounds__(256, 2)
void kq(const float* __restrict__ q, const u16* __restrict__ Wb,
        const float* __restrict__ bq, const u16* __restrict__ Meff,
        const float* __restrict__ bo, float* __restrict__ out)
{
  __shared__ __align__(16) u16 Xs[64][QXST];
  __shared__ __align__(16) u16 SsT[64][QST];

  const int b = blockIdx.y;
  const int t0 = xcd_tile(blockIdx.x) * 64;
  const int tid = threadIdx.x;
  const int lg = (tid >> 4) & 3, lc = tid & 15;
  const int wave = tid >> 6, e0 = wave * 48;
  const u16* Mb = Meff + b * 36864;

  f32x4 acc[3][4];

  gemm_stage_compute(q + (size_t)b * CC * NN, Wb, t0, tid, acc, Xs);
#pragma unroll
  for (int et = 0; et < 3; ++et)
#pragma unroll
    for (int r = 0; r < 4; ++r) {
      int e = e0 + et * 16 + lg * 4 + r;
      float bias = bq[e];
#pragma unroll
      for (int nt = 0; nt < 4; ++nt)
        SsT[nt * 16 + lc][e] = f2bf(acc[et][nt][r] + bias);
    }
  __syncthreads();

#pragma unroll
  for (int ii = 0; ii < 2; ++ii) {
    const int item = ii * 256 + tid;
    const int n = item & 63, h = item >> 6;
    u16* rowp = &SsT[n][h * 24];
    float vals[24];
    float m = -1e30f;
#pragma unroll
    for (int d = 0; d < 24; ++d) {
      vals[d] = bf2f(rowp[d]);
      m = fmaxf(m, vals[d]);
    }
    float s = 0.f;
#pragma unroll
    for (int d = 0; d < 24; ++d) { vals[d] = __expf(vals[d] - m); s += vals[d]; }
    const float inv = 1.f / s;
#pragma unroll
    for (int d = 0; d < 24; ++d) rowp[d] = f2bf(vals[d] * inv);
  }
  __syncthreads();

#pragma unroll
  for (int et = 0; et < 3; ++et)
#pragma unroll
    for (int nt = 0; nt < 4; ++nt) acc[et][nt] = f32x4{0.f, 0.f, 0.f, 0.f};
#pragma unroll
  for (int ks = 0; ks < 6; ++ks) {
    FragU a[3], bb[4];
#pragma unroll
    for (int et = 0; et < 3; ++et)
      a[et].u = *reinterpret_cast<const u16x8*>(
          &Mb[(e0 + et * 16 + lc) * 192 + ks * 32 + lg * 8]);
#pragma unroll
    for (int nt = 0; nt < 4; ++nt)
      bb[nt].u = *reinterpret_cast<const u16x8*>(&SsT[nt * 16 + lc][ks * 32 + lg * 8]);
#pragma unroll
    for (int et = 0; et < 3; ++et)
#pragma unroll
      for (int nt = 0; nt < 4; ++nt)
        acc[et][nt] = __builtin_amdgcn_mfma_f32_16x16x32_bf16(a[et].b, bb[nt].b,
                                                             acc[et][nt], 0, 0, 0);
  }

#pragma unroll
  for (int et = 0; et < 3; ++et)
#pragma unroll
    for (int r = 0; r < 4; ++r) {
      int row = e0 + et * 16 + lg * 4 + r;
      float bias = bo[row];
#pragma unroll
      for (int nt = 0; nt < 4; ++nt)
        out[(size_t)(b * 192 + row) * NN + t0 + nt * 16 + lc] = acc[et][nt][r] + bias;
    }
}

// Convert Wq/Wk/Wv to bf16 (packed [3][192][192]).
__global__ void kz(const float* __restrict__ Wq, const float* __restrict__ Wk,
                   const float* __restrict__ Wv, u16* __restrict__ Wb)
{
  const int i = blockIdx.x * 256 + threadIdx.x;
  if (i < 110592) {
    const float* src = (i < 36864) ? Wq : (i < 73728) ? Wk : Wv;
    Wb[i] = f2bf(src[i % 36864]);
  }
}

extern "C" void kernel_launch(void* const* d_in, const int* in_sizes, int n_in,
                              void* d_out, int out_size, void* d_ws, size_t ws_size,
                              hipStream_t stream)
{
  const float* q  = (const float*)d_in[0];
  const float* k  = (const float*)d_in[1];
  const float* v  = (const float*)d_in[2];
  const float* Wq = (const float*)d_in[3];
  const float* bq = (const float*)d_in[4];
  const float* Wk = (const float*)d_in[5];
  const float* bk = (const float*)d_in[6];
  const float* Wv = (const float*)d_in[7];
  const float* bv = (const float*)d_in[8];
  const float* Wo = (const float*)d_in[9];
  const float* bo = (const float*)d_in[10];
  float* out = (float*)d_out;

  // workspace carve (256B-aligned); total ~56 MB
  char* w = (char*)d_ws;
  u16*   Wb   = (u16*)(w);                     // 221184 B
  u16*   Sexp = (u16*)(w + 221184);            // 25165824 B : [4][256][192][64] bf16
  u16*   Vbuf = (u16*)(w + 25387008);          // 25165824 B : same tile-major layout
  float* part = (float*)(w + 50552832);        // 4915200 B : [4][64][8][600]
  float* ctx  = (float*)(w + 55468032);        // 73728 B : [4][8][576]
  u16*   Meff = (u16*)(w + 55541760);          // 294912 B : [4][192][192] bf16

  hipLaunchKernelGGL(kz, dim3(432), dim3(256), 0, stream, Wq, Wk, Wv, Wb);
  hipLaunchKernelGGL(kproj, dim3(256, 4, 2), dim3(256), 0, stream,
                     k, v, Wb, bk, bv, Sexp, Vbuf);
  hipLaunchKernelGGL(kctx, dim3(64, 4), dim3(512), 0, stream, Sexp, Vbuf, part);
  hipLaunchKernelGGL(kr2, dim3(18, 4), dim3(256), 0, stream, part, ctx);
  hipLaunchKernelGGL(km, dim3(192, 4), dim3(192), 0, stream, Wo, ctx, Meff);
  hipLaunchKernelGGL(kq, dim3(256, 4), dim3(256), 0, stream, q, Wb, bq, Meff, bo, out);
}

// Round 18
// 99.623 us; speedup vs baseline: 1.2134x; 1.0064x over previous
//
#include <hip/hip_runtime.h>

#define CC 192
#define NN 16384
#define XST 198   // kproj Xs stride (elems) = 99 dw (odd) — R9-proven staging layout
#define SST 72    // kproj Ss out-bounce stride (elems) = 36 dw; rows 144B (16B-aligned)
#define QXST 104  // kq Xs stride (elems)
#define QST 200   // kq SsT stride (elems)

typedef unsigned short u16;
typedef __attribute__((ext_vector_type(4))) float f32x4;
typedef __attribute__((ext_vector_type(8))) __bf16 bf16x8;
typedef __attribute__((ext_vector_type(8))) u16 u16x8;
typedef __attribute__((ext_vector_type(4))) u16 u16x4;

union FragU { u16x8 u; bf16x8 b; };

__device__ __forceinline__ u16 f2bf(float f) {
  union { float f; unsigned u; } x; x.f = f;
  return (u16)((x.u + 0x7FFFu + ((x.u >> 16) & 1u)) >> 16);  // RNE
}
__device__ __forceinline__ float bf2f(u16 h) {
  union { unsigned u; float f; } x; x.u = ((unsigned)h) << 16;
  return x.f;
}

// K/V projection — R15-exact (best measured: 50 µs).
// Staging: 12 x f32x4 token-wide loads; transposed b16 LDS writes; hoisted W.
// Output tile-major [b][tile][192][64] bf16 — one contiguous 24.6KB burst per
// block (the strided bf16 write stream was co-limiting; linear = R15's +10us win).
// z=0: Sexp = exp(Wk@k+bk); z=1: Vbuf = Wv@v+bv.
__global__ __launch_bounds__(256, 2)
void kproj(const float* __restrict__ k, const float* __restrict__ v,
           const u16* __restrict__ Wb, const float* __restrict__ bk,
           const float* __restrict__ bv, u16* __restrict__ Sexp,
           u16* __restrict__ Vbuf)
{
  __shared__ __align__(16) u16 buf[192 * SST];   // 27.6 KB; Xs overlay then Ss
  u16 (*Xs)[XST] = reinterpret_cast<u16(*)[XST]>(buf);
  u16 (*Ss)[SST] = reinterpret_cast<u16(*)[SST]>(buf);

  const int b = blockIdx.y, pj = blockIdx.z;
  const int tile = blockIdx.x;                 // 0..255 (64 tokens each)
  const int t0 = tile * 64;
  const int tid = threadIdx.x;
  const int lg = (tid >> 4) & 3, lc = tid & 15;
  const int wave = tid >> 6, e0 = wave * 48;
  const int tg = tid & 15, chq = tid >> 4;     // token-group / channel-quad

  const float* xb = (pj ? v : k) + (size_t)b * CC * NN;
  const u16* Wp = Wb + (pj ? 2 : 1) * 36864;
  const float* bias = pj ? bv : bk;
  u16* outp = pj ? Vbuf : Sexp;

  // ---- issue all X loads (HBM, long pole) ----
  f32x4 p[12];
#pragma unroll
  for (int i = 0; i < 12; ++i)
    p[i] = *reinterpret_cast<const f32x4*>(xb + (size_t)(i * 16 + chq) * NN + t0 + tg * 4);

  // ---- issue all W-frag loads (L2/L3-hot; fly during cvt+barrier) ----
  FragU wfr[6][3];
#pragma unroll
  for (int ks = 0; ks < 6; ++ks)
#pragma unroll
    for (int et = 0; et < 3; ++et)
      wfr[ks][et].u = *reinterpret_cast<const u16x8*>(
          &Wp[(e0 + et * 16 + lc) * 192 + ks * 32 + lg * 8]);

  // ---- cvt + transposed LDS writes ----
#pragma unroll
  for (int i = 0; i < 12; ++i) {
    const int ch = i * 16 + chq;
    Xs[tg * 4 + 0][ch] = f2bf(p[i][0]);
    Xs[tg * 4 + 1][ch] = f2bf(p[i][1]);
    Xs[tg * 4 + 2][ch] = f2bf(p[i][2]);
    Xs[tg * 4 + 3][ch] = f2bf(p[i][3]);
  }
  __syncthreads();

  // ---- 6 MFMA k-steps, zero in-loop global loads ----
  f32x4 acc[3][4];
#pragma unroll
  for (int et = 0; et < 3; ++et)
#pragma unroll
    for (int nt = 0; nt < 4; ++nt) acc[et][nt] = f32x4{0.f, 0.f, 0.f, 0.f};

#pragma unroll
  for (int ks = 0; ks < 6; ++ks) {
    FragU bb[4];
#pragma unroll
    for (int nt = 0; nt < 4; ++nt)
      bb[nt].u = *reinterpret_cast<const u16x8*>(&Xs[nt * 16 + lc][ks * 32 + lg * 8]);
#pragma unroll
    for (int et = 0; et < 3; ++et)
#pragma unroll
      for (int nt = 0; nt < 4; ++nt)
        acc[et][nt] = __builtin_amdgcn_mfma_f32_16x16x32_bf16(wfr[ks][et].b, bb[nt].b,
                                                             acc[et][nt], 0, 0, 0);
  }
  __syncthreads();   // MFMA ds_reads of Xs complete before overwriting as Ss

  // ---- bias (+exp for K) -> Ss[e][tok] bounce ----
#pragma unroll
  for (int et = 0; et < 3; ++et)
#pragma unroll
    for (int r = 0; r < 4; ++r) {
      const int e = e0 + et * 16 + lg * 4 + r;
      const float bbv = bias[e];
#pragma unroll
      for (int nt = 0; nt < 4; ++nt) {
        float val = acc[et][nt][r] + bbv;
        if (!pj) val = __expf(val);        // |kp| small; no max-sub needed
        Ss[e][nt * 16 + lc] = f2bf(val);
      }
    }
  __syncthreads();

  // ---- linear tile write: 24.6KB contiguous, coalesced 1KB/wave-instr ----
  u16* dst = outp + (size_t)(b * 256 + tile) * 12288;
#pragma unroll
  for (int j = 0; j < 6; ++j) {
    const int f0 = tid * 8 + j * 2048;
    const int row = f0 >> 6, tokin = f0 & 63;
    u16x8 vv = *reinterpret_cast<const u16x8*>(&Ss[row][tokin]);
    *reinterpret_cast<u16x8*>(&dst[f0]) = vv;
  }
}

// ctx partials, tile-major inputs; phantom all-ones V-row computes ksum into
// the dv==24 slot for free. block = (256-token slab, batch); 8 waves. No LDS.
__global__ __launch_bounds__(512, 2)
void kctx(const u16* __restrict__ Sexp, const u16* __restrict__ Vbuf,
          float* __restrict__ part)
{
  const int b = blockIdx.y, slab = blockIdx.x;   // 64 slabs x 256 tokens
  const int tid = threadIdx.x;
  const int h = tid >> 6;
  const int lg = (tid >> 4) & 3, lc = tid & 15;

  u16x8 ones;
#pragma unroll
  for (int j = 0; j < 8; ++j) ones[j] = 0x3F80;  // 1.0 bf16

  f32x4 cacc[2][2];
#pragma unroll
  for (int mt = 0; mt < 2; ++mt)
#pragma unroll
    for (int nt = 0; nt < 2; ++nt) cacc[mt][nt] = f32x4{0.f, 0.f, 0.f, 0.f};

#pragma unroll
  for (int ks = 0; ks < 8; ++ks) {
    const int tile = slab * 4 + (ks >> 1);
    const int tokin = (ks & 1) * 32 + lg * 8;
    const size_t tbase = (size_t)(b * 256 + tile) * 12288;
    FragU av[2], bs[2];
#pragma unroll
    for (int mt = 0; mt < 2; ++mt) {
      int row = h * 24 + mt * 16 + lc;   // rows >= h*24+24 feed masked outputs
      if (row > 191) row = 191;
      av[mt].u = *reinterpret_cast<const u16x8*>(&Vbuf[tbase + row * 64 + tokin]);
      bs[mt].u = *reinterpret_cast<const u16x8*>(&Sexp[tbase + row * 64 + tokin]);
    }
    if (lc == 8) av[1].u = ones;         // phantom dv==24 row -> ksum
#pragma unroll
    for (int mt = 0; mt < 2; ++mt)
#pragma unroll
      for (int nt = 0; nt < 2; ++nt)
        cacc[mt][nt] = __builtin_amdgcn_mfma_f32_16x16x32_bf16(
            av[mt].b, bs[nt].b, cacc[mt][nt], 0, 0, 0);
  }

  // part[b][slab][h][dv*24+d], dv<25 (dv==24 = ksum partial); stride 600
  float* pp = part + (((size_t)(b * 64 + slab)) * 8 + h) * 600;
#pragma unroll
  for (int mt = 0; mt < 2; ++mt)
#pragma unroll
    for (int nt = 0; nt < 2; ++nt)
#pragma unroll
      for (int r = 0; r < 4; ++r) {
        const int dv = mt * 16 + lg * 4 + r;
        const int d = nt * 16 + lc;
        if (dv < 25 && d < 24) pp[dv * 24 + d] = cacc[mt][nt][r];
      }
}

// Reduce 64 slab partials + normalize by the phantom ksum row (dv==24)
__global__ void kr2(const float* __restrict__ part, float* __restrict__ ctx)
{
  const int idx = blockIdx.x * 256 + threadIdx.x;
  if (idx >= 4608) return;
  const int b = blockIdx.y;
  const int h = idx / 576, rem = idx % 576;
  const int dv = rem / 24, d = rem % 24;
  float s1 = 0.f, s2 = 0.f;
#pragma unroll 4
  for (int j = 0; j < 64; ++j) {
    const float* pp = part + (((size_t)(b * 64 + j)) * 8 + h) * 600;
    s1 += pp[dv * 24 + d];
    s2 += pp[576 + d];
  }
  ctx[(size_t)b * 4608 + h * 576 + dv * 24 + d] = s1 / s2;
}

// Meff[b][o][h*24+d] = sum_dv Wo[o][h*24+dv] * ctx[b][h][dv*24+d]
__global__ void km(const float* __restrict__ Wo, const float* __restrict__ ctx,
                   u16* __restrict__ Meff)
{
  const int o = blockIdx.x, b = blockIdx.y, j = threadIdx.x;
  const int h = j / 24, d = j % 24;
  const float* Wrow = Wo + o * 192 + h * 24;
  const float* crow = ctx + (size_t)b * 4608 + h * 576 + d;
  float acc = 0.f;
#pragma unroll
  for (int dv = 0; dv < 24; ++dv) acc += Wrow[dv] * crow[dv * 24];
  Meff[(b * 192 + o) * 192 + j] = f2bf(acc);
}

// One 192x192 (W) @ 192x64 (x fp32->bf16) GEMM (R7-exact — empirically best kq).
__device__ __forceinline__ void gemm_stage_compute(
    const float* __restrict__ xb, const u16* __restrict__ Wp,
    int t0, int tid, f32x4 acc[3][4], u16 (*Xs)[QXST])
{
  const int lg = (tid >> 4) & 3, lc = tid & 15;
  const int wave = tid >> 6, e0 = wave * 48;
  const int sn = tid & 63, scg = tid >> 6;
#pragma unroll
  for (int et = 0; et < 3; ++et)
#pragma unroll
    for (int nt = 0; nt < 4; ++nt)
      acc[et][nt] = f32x4{0.f, 0.f, 0.f, 0.f};

#pragma unroll
  for (int hf = 0; hf < 2; ++hf) {
#pragma unroll
    for (int i = 0; i < 6; ++i) {
      int cl = scg * 4 + i * 16;
      const float* src = xb + (size_t)(hf * 96 + cl) * NN + t0 + sn;
      u16x4 p;
      p[0] = f2bf(src[0]);
      p[1] = f2bf(src[NN]);
      p[2] = f2bf(src[2 * NN]);
      p[3] = f2bf(src[3 * NN]);
      *reinterpret_cast<u16x4*>(&Xs[sn][cl]) = p;
    }
    __syncthreads();
#pragma unroll
    for (int ks = 0; ks < 3; ++ks) {
      FragU a[3], bb[4];
#pragma unroll
      for (int et = 0; et < 3; ++et)
        a[et].u = *reinterpret_cast<const u16x8*>(
            &Wp[(e0 + et * 16 + lc) * 192 + hf * 96 + ks * 32 + lg * 8]);
#pragma unroll
      for (int nt = 0; nt < 4; ++nt)
        bb[nt].u = *reinterpret_cast<const u16x8*>(&Xs[nt * 16 + lc][ks * 32 + lg * 8]);
#pragma unroll
      for (int et = 0; et < 3; ++et)
#pragma unroll
        for (int nt = 0; nt < 4; ++nt)
          acc[et][nt] = __builtin_amdgcn_mfma_f32_16x16x32_bf16(a[et].b, bb[nt].b,
                                                               acc[et][nt], 0, 0, 0);
    }
    __syncthreads();
  }
}

// Q kernel (R7-exact, (256,2)): q-proj -> SsT -> softmax over d -> Meff GEMM -> out.
__global__ __launch_bounds__(256, 2)
void kq(const float* __restrict__ q, const u16* __restrict__ Wb,
        const float* __restrict__ bq, const u16* __restrict__ Meff,
        const float* __restrict__ bo, float* __restrict__ out)
{
  __shared__ __align__(16) u16 Xs[64][QXST];
  __shared__ __align__(16) u16 SsT[64][QST];

  const int b = blockIdx.y;
  const int t0 = blockIdx.x * 64;
  const int tid = threadIdx.x;
  const int lg = (tid >> 4) & 3, lc = tid & 15;
  const int wave = tid >> 6, e0 = wave * 48;
  const u16* Mb = Meff + b * 36864;

  f32x4 acc[3][4];

  gemm_stage_compute(q + (size_t)b * CC * NN, Wb, t0, tid, acc, Xs);
#pragma unroll
  for (int et = 0; et < 3; ++et)
#pragma unroll
    for (int r = 0; r < 4; ++r) {
      int e = e0 + et * 16 + lg * 4 + r;
      float bias = bq[e];
#pragma unroll
      for (int nt = 0; nt < 4; ++nt)
        SsT[nt * 16 + lc][e] = f2bf(acc[et][nt][r] + bias);
    }
  __syncthreads();

#pragma unroll
  for (int ii = 0; ii < 2; ++ii) {
    const int item = ii * 256 + tid;
    const int n = item & 63, h = item >> 6;
    u16* rowp = &SsT[n][h * 24];
    float vals[24];
    float m = -1e30f;
#pragma unroll
    for (int d = 0; d < 24; ++d) {
      vals[d] = bf2f(rowp[d]);
      m = fmaxf(m, vals[d]);
    }
    float s = 0.f;
#pragma unroll
    for (int d = 0; d < 24; ++d) { vals[d] = __expf(vals[d] - m); s += vals[d]; }
    const float inv = 1.f / s;
#pragma unroll
    for (int d = 0; d < 24; ++d) rowp[d] = f2bf(vals[d] * inv);
  }
  __syncthreads();

#pragma unroll
  for (int et = 0; et < 3; ++et)
#pragma unroll
    for (int nt = 0; nt < 4; ++nt) acc[et][nt] = f32x4{0.f, 0.f, 0.f, 0.f};
#pragma unroll
  for (int ks = 0; ks < 6; ++ks) {
    FragU a[3], bb[4];
#pragma unroll
    for (int et = 0; et < 3; ++et)
      a[et].u = *reinterpret_cast<const u16x8*>(
          &Mb[(e0 + et * 16 + lc) * 192 + ks * 32 + lg * 8]);
#pragma unroll
    for (int nt = 0; nt < 4; ++nt)
      bb[nt].u = *reinterpret_cast<const u16x8*>(&SsT[nt * 16 + lc][ks * 32 + lg * 8]);
#pragma unroll
    for (int et = 0; et < 3; ++et)
#pragma unroll
      for (int nt = 0; nt < 4; ++nt)
        acc[et][nt] = __builtin_amdgcn_mfma_f32_16x16x32_bf16(a[et].b, bb[nt].b,
                                                             acc[et][nt], 0, 0, 0);
  }

#pragma unroll
  for (int et = 0; et < 3; ++et)
#pragma unroll
    for (int r = 0; r < 4; ++r) {
      int row = e0 + et * 16 + lg * 4 + r;
      float bias = bo[row];
#pragma unroll
      for (int nt = 0; nt < 4; ++nt)
        out[(size_t)(b * 192 + row) * NN + t0 + nt * 16 + lc] = acc[et][nt][r] + bias;
    }
}

// Convert Wq/Wk/Wv to bf16 (packed [3][192][192]) — vectorized f32x4 -> u16x4.
// 110592 elems = 108 blocks x 256 threads x 4; 36864 % 4 == 0 so chunks never
// straddle a source-tensor boundary.
__global__ void kz(const float* __restrict__ Wq, const float* __restrict__ Wk,
                   const float* __restrict__ Wv, u16* __restrict__ Wb)
{
  const int i4 = (blockIdx.x * 256 + threadIdx.x) * 4;
  if (i4 >= 110592) return;
  const float* src = (i4 < 36864) ? Wq : (i4 < 73728) ? Wk : Wv;
  f32x4 vv = *reinterpret_cast<const f32x4*>(&src[i4 % 36864]);
  u16x4 o;
  o[0] = f2bf(vv[0]); o[1] = f2bf(vv[1]); o[2] = f2bf(vv[2]); o[3] = f2bf(vv[3]);
  *reinterpret_cast<u16x4*>(&Wb[i4]) = o;
}

extern "C" void kernel_launch(void* const* d_in, const int* in_sizes, int n_in,
                              void* d_out, int out_size, void* d_ws, size_t ws_size,
                              hipStream_t stream)
{
  const float* q  = (const float*)d_in[0];
  const float* k  = (const float*)d_in[1];
  const float* v  = (const float*)d_in[2];
  const float* Wq = (const float*)d_in[3];
  const float* bq = (const float*)d_in[4];
  const float* Wk = (const float*)d_in[5];
  const float* bk = (const float*)d_in[6];
  const float* Wv = (const float*)d_in[7];
  const float* bv = (const float*)d_in[8];
  const float* Wo = (const float*)d_in[9];
  const float* bo = (const float*)d_in[10];
  float* out = (float*)d_out;

  // workspace carve (256B-aligned); total ~56 MB
  char* w = (char*)d_ws;
  u16*   Wb   = (u16*)(w);                     // 221184 B
  u16*   Sexp = (u16*)(w + 221184);            // 25165824 B : [4][256][192][64] bf16
  u16*   Vbuf = (u16*)(w + 25387008);          // 25165824 B : same tile-major layout
  float* part = (float*)(w + 50552832);        // 4915200 B : [4][64][8][600]
  float* ctx  = (float*)(w + 55468032);        // 73728 B : [4][8][576]
  u16*   Meff = (u16*)(w + 55541760);          // 294912 B : [4][192][192] bf16

  hipLaunchKernelGGL(kz, dim3(108), dim3(256), 0, stream, Wq, Wk, Wv, Wb);
  hipLaunchKernelGGL(kproj, dim3(256, 4, 2), dim3(256), 0, stream,
                     k, v, Wb, bk, bv, Sexp, Vbuf);
  hipLaunchKernelGGL(kctx, dim3(64, 4), dim3(512), 0, stream, Sexp, Vbuf, part);
  hipLaunchKernelGGL(kr2, dim3(18, 4), dim3(256), 0, stream, part, ctx);
  hipLaunchKernelGGL(km, dim3(192, 4), dim3(192), 0, stream, Wo, ctx, Meff);
  hipLaunchKernelGGL(kq, dim3(256, 4), dim3(256), 0, stream, q, Wb, bq, Meff, bo, out);
}